// Round 2
// baseline (1294.571 us; speedup 1.0000x reference)
//
#include <hip/hip_runtime.h>
#include <cstdint>
#include <cstddef>

typedef short short8 __attribute__((ext_vector_type(8)));
typedef float floatx4 __attribute__((ext_vector_type(4)));
typedef unsigned short u16;

__device__ __forceinline__ u16 f2bf(float f) {
    unsigned u = __float_as_uint(f);
    u += 0x7FFFu + ((u >> 16) & 1u);
    return (u16)(u >> 16);
}
__device__ __forceinline__ float bf2f(u16 h) {
    return __uint_as_float(((unsigned)h) << 16);
}

// ---------------------------------------------------------------------------
// Kernel 1: x [4][72][32][32][32] f32 (NCDHW)  ->  xt [4][32][32][32][72] bf16
// ---------------------------------------------------------------------------
__global__ __launch_bounds__(256) void k_transpose_x(const float* __restrict__ x,
                                                     u16* __restrict__ xt) {
    __shared__ float tile[72 * 33];
    const int bx = blockIdx.x;               // ((b*32+d)*32+h)
    const int tid = threadIdx.x;
    const int b = bx >> 10, d = (bx >> 5) & 31, h = bx & 31;
    const float* src = x + (size_t)b * 72 * 32768 + d * 1024 + h * 32;
    for (int e = tid; e < 2304; e += 256) {
        int ci = e >> 5, w = e & 31;
        tile[ci * 33 + w] = src[(size_t)ci * 32768 + w];
    }
    __syncthreads();
    u16* dst = xt + (size_t)bx * 2304;
    for (int e = tid; e < 2304; e += 256) {
        int w = e / 72, ci = e - w * 72;
        dst[e] = f2bf(tile[ci * 33 + w]);
    }
}

// ---------------------------------------------------------------------------
// Kernel 2: W [176][72][5][5][5] f32 -> wt bf16 per-lane B-fragment layout:
//   wt[kd][kh][kblk(12)][nblk(11)][lane(64)][8]   (linear in kk = kh*12+kb)
// ---------------------------------------------------------------------------
__global__ __launch_bounds__(256) void k_prep_w(const float* __restrict__ W,
                                                u16* __restrict__ wt) {
    const int gid = blockIdx.x * 256 + threadIdx.x;   // 825*256 = 211200 = 3300 frags * 64
    const int frag = gid >> 6, lane = gid & 63;
    const int nb = frag % 11;
    int t = frag / 11;
    const int kb = t % 12;
    t = t / 12;
    const int kh = t % 5, kd = t / 5;
    const int n = lane & 15, q8 = (lane >> 4) * 8;
    const int co = nb * 16 + n;
    u16 v[8] __attribute__((aligned(16)));
    #pragma unroll
    for (int j = 0; j < 8; ++j) {
        int k = kb * 32 + q8 + j;
        u16 r = 0;
        if (k < 360) {
            int kw = k / 72, ci = k - kw * 72;
            r = f2bf(W[((size_t)co * 72 + ci) * 125 + kd * 25 + kh * 5 + kw]);
        }
        v[j] = r;
    }
    *(uint4*)(wt + (size_t)gid * 8) = *(const uint4*)v;
}

// ---------------------------------------------------------------------------
// Kernel 3: implicit-GEMM conv + fused gating, barrier-free inner loop.
// Grid 256 = (b:4, d:32, ht:2). Block: 512 threads = 8 waves.
// Block tile: 16 h-rows x 32 w x 176 co; wave: 2 h-rows x 32 w x 176 co.
// B (weights) live per-wave in REGISTERS, triple-buffered with a full
// 2-step prefetch distance (~2800 device cycles issue-to-use): no
// __syncthreads per kb-step, no vmcnt(0) drains, waves free-run.
// wt is 3.3 MB -> L2-resident; per-wave loads hit L2.
// ---------------------------------------------------------------------------
#define LP 2624

#define MFMA_BF16 __builtin_amdgcn_mfma_f32_16x16x32_bf16

// One kb-step: consume Bc (loaded 2 steps ago), issue loads for step kkc+2
// into Bn. kkc is block-uniform (SALU); prefetch address is linear in kk.
#define STEP(Bc, Bn, kkc) do {                                                     \
    const int kh_ = (kkc) / 12;                                                    \
    const int kb_ = (kkc) - 12 * kh_;                                              \
    const u16* ap_ = sxA + kh_ * LP + kb_ * 32;                                    \
    short8 A0_ = *(const short8*)(ap_);                                            \
    short8 A1_ = *(const short8*)(ap_ + 1152);                                     \
    short8 A2_ = *(const short8*)(ap_ + LP);                                       \
    short8 A3_ = *(const short8*)(ap_ + LP + 1152);                                \
    const int kkn_ = ((kkc) + 2 < 60) ? ((kkc) + 2) : 59;                          \
    const u16* gp_ = wt_kd + (size_t)kkn_ * 5632 + lane * 8;                       \
    _Pragma("unroll")                                                              \
    for (int j = 0; j < 11; ++j) Bn[j] = *(const short8*)(gp_ + j * 512);          \
    _Pragma("unroll")                                                              \
    for (int j = 0; j < 11; ++j) {                                                 \
        acc[0][j] = MFMA_BF16(A0_, Bc[j], acc[0][j], 0, 0, 0);                     \
        acc[1][j] = MFMA_BF16(A1_, Bc[j], acc[1][j], 0, 0, 0);                     \
        acc[2][j] = MFMA_BF16(A2_, Bc[j], acc[2][j], 0, 0, 0);                     \
        acc[3][j] = MFMA_BF16(A3_, Bc[j], acc[3][j], 0, 0, 0);                     \
    }                                                                              \
} while (0)

__global__ __launch_bounds__(512, 2) void k_conv(const u16* __restrict__ xt,
                                                 const u16* __restrict__ wt,
                                                 const float* __restrict__ scalar_bias,
                                                 const float* __restrict__ gate_bias,
                                                 u16* __restrict__ zt) {
    __shared__ __align__(16) u16 sx[20 * LP];    // A tile: 16 out h-rows + 4 halo (104,960 B)
    const int bx = blockIdx.x;
    const int ht = bx & 1, d = (bx >> 1) & 31, b = bx >> 6;
    const int h0 = ht * 16;
    const int tid = threadIdx.x, lane = tid & 63, wv = tid >> 6;
    const int c15 = lane & 15, q = lane >> 4;

    floatx4 acc[4][11];
    #pragma unroll
    for (int i = 0; i < 4; ++i) {
        #pragma unroll
        for (int j = 0; j < 11; ++j) acc[i][j] = (floatx4){0.f, 0.f, 0.f, 0.f};
    }

    const int laneA = c15 * 72 + q * 8;
    const u16* sxA = &sx[2 * wv * LP + laneA];

    short8 B0[11], B1[11], B2[11];

    for (int kd = 0; kd < 5; ++kd) {
        const int dp = d + kd - 2;
        if (dp < 0 || dp >= 32) continue;            // block-uniform
        // ---- stage one d-slice into LDS (zero-fill halos & k-pad region) ----
        const u16* srcbase = xt + (size_t)((b * 32 + dp) * 32) * 2304;
        __syncthreads();    // protect sx against waves still reading prev slice
        for (int idx = tid; idx < 20 * 328; idx += 512) {
            int r = idx / 328, c = idx - r * 328;
            int hp = h0 + r - 2;
            uint4 val = make_uint4(0u, 0u, 0u, 0u);
            if (hp >= 0 && hp < 32 && c >= 18 && c < 306)
                val = *(const uint4*)(srcbase + (size_t)hp * 2304 + (c * 8 - 144));
            *(uint4*)(&sx[r * LP + c * 8]) = val;
        }
        const u16* wt_kd = wt + (size_t)kd * 5 * 67584;   // 12*11*512 = 67584 per (kd,kh)
        // preload B for steps 0 and 1 (latency exposed once per kd, ~L2-hit)
        {
            const u16* g0 = wt_kd + lane * 8;
            #pragma unroll
            for (int j = 0; j < 11; ++j) B0[j] = *(const short8*)(g0 + j * 512);
            const u16* g1 = wt_kd + 5632 + lane * 8;
            #pragma unroll
            for (int j = 0; j < 11; ++j) B1[j] = *(const short8*)(g1 + j * 512);
        }
        __syncthreads();

        // ---- 60 kb-steps (kh 0..4 x kb 0..11), no barriers ----
        #pragma unroll 1
        for (int kk = 0; kk < 60; kk += 3) {
            STEP(B0, B2, kk);
            STEP(B1, B0, kk + 1);
            STEP(B2, B1, kk + 2);
        }
    }

    // ---- epilogue: fused gate + bf16 store to zt ----
    // C/D layout: col(co) = lane&15, row(pos) = q*4 + reg.
    const float sb = scalar_bias[c15];
    int   slA[9];
    float gbA[9];
    #pragma unroll
    for (int nb = 1; nb <= 8; ++nb) {
        int idx = (nb - 1) * 16 + c15;                       // co_f - 16
        int mul = (nb <= 3) ? (idx / 3) : (16 + (idx - 48) / 5);
        slA[nb] = (lane & 48) | (mul & 15);
        gbA[nb] = gate_bias[mul];
    }
    #pragma unroll
    for (int mi = 0; mi < 4; ++mi) {
        const int hl = 2 * wv + (mi >> 1);
        const int wh = mi & 1;
        const size_t zrow0 = (size_t)((b * 32 + d) * 32 + (h0 + hl)) * 32;
        #pragma unroll
        for (int r = 0; r < 4; ++r) {
            const int w = wh * 16 + q * 4 + r;
            u16* zp = zt + (zrow0 + w) * 144;
            zp[c15] = f2bf(fmaxf(acc[mi][0][r] + sb, 0.f));   // scalar field: relu+bias
            const float g9v  = acc[mi][9][r];
            const float g10v = acc[mi][10][r];
            #pragma unroll
            for (int nb = 1; nb <= 8; ++nb) {
                float ys = __shfl((nb <= 3) ? g9v : g10v, slA[nb], 64);
                float g  = 1.f / (1.f + __expf(-(ys + gbA[nb])));
                zp[nb * 16 + c15] = f2bf(acc[mi][nb][r] * g);
            }
        }
    }
}

// ---------------------------------------------------------------------------
// Kernel 4: stride-2 5x5x5 Gaussian low-pass.
// zt [b][d][h][w][144] bf16 -> out [4][144][16][16][16] f32 (NCDHW).
// ---------------------------------------------------------------------------
__global__ __launch_bounds__(256) void k_lowpass(const u16* __restrict__ zt,
                                                 float* __restrict__ out) {
    const int gid = blockIdx.x * 256 + threadIdx.x;   // 1152*256 = 294912
    const int row = gid / 288;
    const int it  = gid - row * 288;
    const int c8 = it >> 4, ow = it & 15;
    const int oh = row & 15, od = (row >> 4) & 15, b = row >> 8;
    const float lw[5] = {0.03208210f, 0.23705644f, 0.46172277f, 0.23705644f, 0.03208210f};
    float a[8];
    #pragma unroll
    for (int j = 0; j < 8; ++j) a[j] = 0.f;
    for (int kd = 0; kd < 5; ++kd) {
        const int dz = 2 * od + kd - 2;
        if (dz < 0 || dz >= 32) continue;
        for (int kh = 0; kh < 5; ++kh) {
            const int hz = 2 * oh + kh - 2;
            if (hz < 0 || hz >= 32) continue;
            const float whd = lw[kd] * lw[kh];
            const u16* base = zt + (size_t)((b * 32 + dz) * 32 + hz) * 32 * 144 + c8 * 8;
            #pragma unroll
            for (int kw = 0; kw < 5; ++kw) {
                const int wz = 2 * ow + kw - 2;
                if (wz < 0 || wz >= 32) continue;
                const float wt3 = whd * lw[kw];
                u16 v[8] __attribute__((aligned(16)));
                *(uint4*)v = *(const uint4*)(base + (size_t)wz * 144);
                #pragma unroll
                for (int j = 0; j < 8; ++j) a[j] += wt3 * bf2f(v[j]);
            }
        }
    }
    const int c0 = c8 * 8;
    float* op = out + ((size_t)b * 144 + c0) * 4096 + od * 256 + oh * 16 + ow;
    #pragma unroll
    for (int j = 0; j < 8; ++j) op[(size_t)j * 4096] = a[j];
}

// ---------------------------------------------------------------------------
extern "C" void kernel_launch(void* const* d_in, const int* in_sizes, int n_in,
                              void* d_out, int out_size, void* d_ws, size_t ws_size,
                              hipStream_t stream) {
    const float* x  = (const float*)d_in[0];   // 4*72*32^3
    const float* W  = (const float*)d_in[1];   // 176*72*125
    const float* sb = (const float*)d_in[2];   // 16
    const float* gb = (const float*)d_in[3];   // 32
    float* out = (float*)d_out;                // 4*144*16^3 f32

    char* ws = (char*)d_ws;
    u16* xt = (u16*)(ws);                      // 18,874,368 B
    u16* wt = (u16*)(ws + 18874368);           //  3,379,200 B
    u16* zt = (u16*)(ws + 22253568);           // 37,748,736 B  (total ~60 MB)

    hipLaunchKernelGGL(k_transpose_x, dim3(4096), dim3(256), 0, stream, x, xt);
    hipLaunchKernelGGL(k_prep_w,      dim3(825),  dim3(256), 0, stream, W, wt);
    hipLaunchKernelGGL(k_conv,        dim3(256),  dim3(512), 0, stream, xt, wt, sb, gb, zt);
    hipLaunchKernelGGL(k_lowpass,     dim3(1152), dim3(256), 0, stream, zt, out);
}

// Round 3
// 494.013 us; speedup vs baseline: 2.6205x; 2.6205x over previous
//
#include <hip/hip_runtime.h>
#include <cstdint>
#include <cstddef>

typedef short short8 __attribute__((ext_vector_type(8)));
typedef float floatx4 __attribute__((ext_vector_type(4)));
typedef unsigned short u16;

__device__ __forceinline__ u16 f2bf(float f) {
    unsigned u = __float_as_uint(f);
    u += 0x7FFFu + ((u >> 16) & 1u);
    return (u16)(u >> 16);
}
__device__ __forceinline__ float bf2f(u16 h) {
    return __uint_as_float(((unsigned)h) << 16);
}

// async global->LDS, 16B per lane; LDS base must be wave-uniform.
__device__ __forceinline__ void gload_lds16(const u16* g, u16* l) {
    __builtin_amdgcn_global_load_lds(
        (const __attribute__((address_space(1))) void*)g,
        (__attribute__((address_space(3))) void*)l, 16, 0, 0);
}

// ---------------------------------------------------------------------------
// Kernel 1: x [4][72][32][32][32] f32 (NCDHW)  ->  xt [4][32][32][32][72] bf16
// ---------------------------------------------------------------------------
__global__ __launch_bounds__(256) void k_transpose_x(const float* __restrict__ x,
                                                     u16* __restrict__ xt) {
    __shared__ float tile[72 * 33];
    const int bx = blockIdx.x;               // ((b*32+d)*32+h)
    const int tid = threadIdx.x;
    const int b = bx >> 10, d = (bx >> 5) & 31, h = bx & 31;
    const float* src = x + (size_t)b * 72 * 32768 + d * 1024 + h * 32;
    for (int e = tid; e < 2304; e += 256) {
        int ci = e >> 5, w = e & 31;
        tile[ci * 33 + w] = src[(size_t)ci * 32768 + w];
    }
    __syncthreads();
    u16* dst = xt + (size_t)bx * 2304;
    for (int e = tid; e < 2304; e += 256) {
        int w = e / 72, ci = e - w * 72;
        dst[e] = f2bf(tile[ci * 33 + w]);
    }
}

// ---------------------------------------------------------------------------
// Kernel 2: W [176][72][5][5][5] f32 -> wt bf16 per-lane B-fragment layout:
//   wt[kd][kh][kblk(12)][nblk(11)][lane(64)][8]   (linear in kk = kh*12+kb)
// ---------------------------------------------------------------------------
__global__ __launch_bounds__(256) void k_prep_w(const float* __restrict__ W,
                                                u16* __restrict__ wt) {
    const int gid = blockIdx.x * 256 + threadIdx.x;   // 825*256 = 211200 = 3300 frags * 64
    const int frag = gid >> 6, lane = gid & 63;
    const int nb = frag % 11;
    int t = frag / 11;
    const int kb = t % 12;
    t = t / 12;
    const int kh = t % 5, kd = t / 5;
    const int n = lane & 15, q8 = (lane >> 4) * 8;
    const int co = nb * 16 + n;
    u16 v[8] __attribute__((aligned(16)));
    #pragma unroll
    for (int j = 0; j < 8; ++j) {
        int k = kb * 32 + q8 + j;
        u16 r = 0;
        if (k < 360) {
            int kw = k / 72, ci = k - kw * 72;
            r = f2bf(W[((size_t)co * 72 + ci) * 125 + kd * 25 + kh * 5 + kw]);
        }
        v[j] = r;
    }
    *(uint4*)(wt + (size_t)gid * 8) = *(const uint4*)v;
}

// ---------------------------------------------------------------------------
// Kernel 3: implicit-GEMM conv + fused gating.
// Grid 256 = (b:4, d:32, ht:2). Block: 512 threads = 8 waves.
// Block tile: 16 h-rows x 32 w x 176 co; wave: 2 h-rows x 32 w x 176 co.
// B (weights): 4-deep LDS ring, staged via global_load_lds with pair-cadence
// barriers. Stages for pair P+1 are issued right AFTER pair P's barrier and
// drained at pair P+1's barrier -> the vmcnt(0) inside __syncthreads waits
// on loads issued a full pair (~4000+ cyc) earlier: drain cost ~0.
// Disjointness: pair P reads bufs {2P,2P+1}%4, stages {2P+2,2P+3}%4.
// ---------------------------------------------------------------------------
#define LP 2624
#define MFMA_BF16 __builtin_amdgcn_mfma_f32_16x16x32_bf16

// Stage the two kb-steps s0_, s0_+1 into ring bufs (s0_)&3, (s0_+1)&3.
// 22 chunks of 1024B over 8 waves (waves 0..5 take a 3rd chunk).
#define STAGE_PAIR(s0_) do {                                                       \
    _Pragma("unroll")                                                              \
    for (int cc = 0; cc < 3; ++cc) {                                               \
        const int c_  = wv + cc * 8;                                               \
        const int st_ = (s0_) + (c_ >= 11 ? 1 : 0);                                \
        const int nb_ = (c_ >= 11) ? (c_ - 11) : c_;                               \
        if (c_ < 22 && st_ < 60)                                                   \
            gload_lds16(wt_kd + (size_t)st_ * 5632 + nb_ * 512 + lane * 8,         \
                        sB + (st_ & 3) * 5632 + nb_ * 512);                        \
    }                                                                              \
} while (0)

// One kb-step: 4 A-frag LDS reads + 11 B-frag LDS reads + 44 MFMAs.
#define CSTEP(aoff_, buf_) do {                                                    \
    const u16* ap_ = sxA + (aoff_);                                                \
    short8 A0_ = *(const short8*)(ap_);                                            \
    short8 A1_ = *(const short8*)(ap_ + 1152);                                     \
    short8 A2_ = *(const short8*)(ap_ + LP);                                       \
    short8 A3_ = *(const short8*)(ap_ + LP + 1152);                                \
    const u16* bb_ = sB + (buf_) * 5632 + lane * 8;                                \
    _Pragma("unroll")                                                              \
    for (int j = 0; j < 11; ++j) {                                                 \
        short8 bv = *(const short8*)(bb_ + j * 512);                               \
        acc[0][j] = MFMA_BF16(A0_, bv, acc[0][j], 0, 0, 0);                        \
        acc[1][j] = MFMA_BF16(A1_, bv, acc[1][j], 0, 0, 0);                        \
        acc[2][j] = MFMA_BF16(A2_, bv, acc[2][j], 0, 0, 0);                        \
        acc[3][j] = MFMA_BF16(A3_, bv, acc[3][j], 0, 0, 0);                        \
    }                                                                              \
} while (0)

__global__ __launch_bounds__(512, 2) void k_conv(const u16* __restrict__ xt,
                                                 const u16* __restrict__ wt,
                                                 const float* __restrict__ scalar_bias,
                                                 const float* __restrict__ gate_bias,
                                                 u16* __restrict__ zt) {
    __shared__ __align__(16) u16 sx[20 * LP];    // A tile: 16 out h-rows + 4 halo (104,960 B)
    __shared__ __align__(16) u16 sB[4 * 5632];   // B ring: 4 x 11,264 B = 45,056 B
    const int bx = blockIdx.x;
    const int ht = bx & 1, d = (bx >> 1) & 31, b = bx >> 6;
    const int h0 = ht * 16;
    const int tid = threadIdx.x, lane = tid & 63, wv = tid >> 6;
    const int c15 = lane & 15, q = lane >> 4;

    floatx4 acc[4][11];
    #pragma unroll
    for (int i = 0; i < 4; ++i) {
        #pragma unroll
        for (int j = 0; j < 11; ++j) acc[i][j] = (floatx4){0.f, 0.f, 0.f, 0.f};
    }

    const int laneA = c15 * 72 + q * 8;
    const u16* sxA = &sx[2 * wv * LP + laneA];

    for (int kd = 0; kd < 5; ++kd) {
        const int dp = d + kd - 2;
        if (dp < 0 || dp >= 32) continue;            // block-uniform
        const u16* wt_kd = wt + (size_t)kd * 5 * 67584;   // 12*11*512 = 67584 u16 per (kd,kh)

        __syncthreads();   // all waves done reading sx/sB from previous kd-slice
        // ---- stage one d-slice of A into LDS (zero-fill halos & k-pad) ----
        const u16* srcbase = xt + (size_t)((b * 32 + dp) * 32) * 2304;
        for (int idx = tid; idx < 20 * 328; idx += 512) {
            int r = idx / 328, c = idx - r * 328;
            int hp = h0 + r - 2;
            uint4 val = make_uint4(0u, 0u, 0u, 0u);
            if (hp >= 0 && hp < 32 && c >= 18 && c < 306)
                val = *(const uint4*)(srcbase + (size_t)hp * 2304 + (c * 8 - 144));
            *(uint4*)(&sx[r * LP + c * 8]) = val;
        }
        STAGE_PAIR(0);     // steps 0,1 -> bufs 0,1
        __syncthreads();   // drains sx writes + first B pair (once per kd-slice)

        // ---- 60 kb-steps (kk = kh*12+kb), barrier every 2 steps ----
        int kh = 0, kb = 0;
        #pragma unroll 1
        for (int kp = 0; kp < 60; kp += 2) {
            if (kp) __syncthreads();   // drains stages issued one pair ago (free)
            STAGE_PAIR(kp + 2);        // next pair -> bufs (kp+2)&3, (kp+3)&3
            const int aoff = kh * LP + kb * 32;
            CSTEP(aoff,      kp & 3);
            CSTEP(aoff + 32, (kp + 1) & 3);
            kb += 2;
            if (kb == 12) { kb = 0; ++kh; }
        }
    }

    // ---- epilogue: fused gate + bf16 store to zt ----
    // C/D layout: col(co) = lane&15, row(pos) = q*4 + reg.
    const float sb = scalar_bias[c15];
    int   slA[9];
    float gbA[9];
    #pragma unroll
    for (int nb = 1; nb <= 8; ++nb) {
        int idx = (nb - 1) * 16 + c15;                       // co_f - 16
        int mul = (nb <= 3) ? (idx / 3) : (16 + (idx - 48) / 5);
        slA[nb] = (lane & 48) | (mul & 15);
        gbA[nb] = gate_bias[mul];
    }
    #pragma unroll
    for (int mi = 0; mi < 4; ++mi) {
        const int hl = 2 * wv + (mi >> 1);
        const int wh = mi & 1;
        const size_t zrow0 = (size_t)((b * 32 + d) * 32 + (h0 + hl)) * 32;
        #pragma unroll
        for (int r = 0; r < 4; ++r) {
            const int w = wh * 16 + q * 4 + r;
            u16* zp = zt + (zrow0 + w) * 144;
            zp[c15] = f2bf(fmaxf(acc[mi][0][r] + sb, 0.f));   // scalar field: relu+bias
            const float g9v  = acc[mi][9][r];
            const float g10v = acc[mi][10][r];
            #pragma unroll
            for (int nb = 1; nb <= 8; ++nb) {
                float ys = __shfl((nb <= 3) ? g9v : g10v, slA[nb], 64);
                float g  = 1.f / (1.f + __expf(-(ys + gbA[nb])));
                zp[nb * 16 + c15] = f2bf(acc[mi][nb][r] * g);
            }
        }
    }
}

// ---------------------------------------------------------------------------
// Kernel 4: stride-2 5x5x5 Gaussian low-pass.
// zt [b][d][h][w][144] bf16 -> out [4][144][16][16][16] f32 (NCDHW).
// ---------------------------------------------------------------------------
__global__ __launch_bounds__(256) void k_lowpass(const u16* __restrict__ zt,
                                                 float* __restrict__ out) {
    const int gid = blockIdx.x * 256 + threadIdx.x;   // 1152*256 = 294912
    const int row = gid / 288;
    const int it  = gid - row * 288;
    const int c8 = it >> 4, ow = it & 15;
    const int oh = row & 15, od = (row >> 4) & 15, b = row >> 8;
    const float lw[5] = {0.03208210f, 0.23705644f, 0.46172277f, 0.23705644f, 0.03208210f};
    float a[8];
    #pragma unroll
    for (int j = 0; j < 8; ++j) a[j] = 0.f;
    for (int kd = 0; kd < 5; ++kd) {
        const int dz = 2 * od + kd - 2;
        if (dz < 0 || dz >= 32) continue;
        for (int kh = 0; kh < 5; ++kh) {
            const int hz = 2 * oh + kh - 2;
            if (hz < 0 || hz >= 32) continue;
            const float whd = lw[kd] * lw[kh];
            const u16* base = zt + (size_t)((b * 32 + dz) * 32 + hz) * 32 * 144 + c8 * 8;
            #pragma unroll
            for (int kw = 0; kw < 5; ++kw) {
                const int wz = 2 * ow + kw - 2;
                if (wz < 0 || wz >= 32) continue;
                const float wt3 = whd * lw[kw];
                u16 v[8] __attribute__((aligned(16)));
                *(uint4*)v = *(const uint4*)(base + (size_t)wz * 144);
                #pragma unroll
                for (int j = 0; j < 8; ++j) a[j] += wt3 * bf2f(v[j]);
            }
        }
    }
    const int c0 = c8 * 8;
    float* op = out + ((size_t)b * 144 + c0) * 4096 + od * 256 + oh * 16 + ow;
    #pragma unroll
    for (int j = 0; j < 8; ++j) op[(size_t)j * 4096] = a[j];
}

// ---------------------------------------------------------------------------
extern "C" void kernel_launch(void* const* d_in, const int* in_sizes, int n_in,
                              void* d_out, int out_size, void* d_ws, size_t ws_size,
                              hipStream_t stream) {
    const float* x  = (const float*)d_in[0];   // 4*72*32^3
    const float* W  = (const float*)d_in[1];   // 176*72*125
    const float* sb = (const float*)d_in[2];   // 16
    const float* gb = (const float*)d_in[3];   // 32
    float* out = (float*)d_out;                // 4*144*16^3 f32

    char* ws = (char*)d_ws;
    u16* xt = (u16*)(ws);                      // 18,874,368 B
    u16* wt = (u16*)(ws + 18874368);           //  3,379,200 B
    u16* zt = (u16*)(ws + 22253568);           // 37,748,736 B  (total ~60 MB)

    hipLaunchKernelGGL(k_transpose_x, dim3(4096), dim3(256), 0, stream, x, xt);
    hipLaunchKernelGGL(k_prep_w,      dim3(825),  dim3(256), 0, stream, W, wt);
    hipLaunchKernelGGL(k_conv,        dim3(256),  dim3(512), 0, stream, xt, wt, sb, gb, zt);
    hipLaunchKernelGGL(k_lowpass,     dim3(1152), dim3(256), 0, stream, zt, out);
}